// Round 4
// baseline (2509.175 us; speedup 1.0000x reference)
//
#include <hip/hip_runtime.h>
#include <cfloat>

#define B_  8
#define N_  2048
#define H_  256
#define L_  4
#define K_  16
#define G_  512
#define M0_ 256
#define M1_ 128
#define C_  128
#define BN_ 16384   // B_*N_
#define KP_ 768     // packed split-bf16 K (3*H_)

#define TW_  256    // gram col-tile width
#define RWG_ 32     // gram rows per workgroup
#define CAP_ 32     // candidate queue capacity per row

typedef unsigned short ushort_t;
typedef __attribute__((ext_vector_type(8))) short short8;
typedef __attribute__((ext_vector_type(4))) float f32x4;

// ---------------- workspace layout (bytes) ----------------
#define OFF_H     ((size_t)0)            // 16 MB  h (fp32, persistent)
#define OFF_APACK ((size_t)16777216)     // 25.2 MB  P-pack [hi,lo,hi]
#define OFF_BPACK ((size_t)41943040)     // 25.2 MB  Q-pack [hi,hi,lo] (gram)
#define OFF_SQ    ((size_t)67108864)     // 64 KB
#define OFF_IDX   ((size_t)67174400)     // 1 MB
#define OFF_STATS ((size_t)68222976)     // 4 KB (512 doubles)
#define OFF_SCSH  ((size_t)68227072)     // 2 KB
#define OFF_BCAT  ((size_t)68229120)     // 2 KB
#define OFF_P0    ((size_t)68231168)     // 16 KB
#define OFF_P1    ((size_t)68247552)
#define OFF_P2    ((size_t)68255744)
#define OFF_D     ((size_t)69206016)     // big region multiplexed below (D no longer materialized)
#define OFF_T     (OFF_D + (size_t)0)           // 16 MB (alive gather_max -> bn2)
#define OFF_XB    (OFF_D + (size_t)33554432)    // 16 MB (alive bn1 -> sqnorm)
#define OFF_UV    (OFF_D + (size_t)50331648)    // 33.5 MB (alive uv gemm -> gather); also y
#define OFF_QW    (OFF_D + (size_t)83886080)    // 0.79 MB weight packs
#define OFF_PMAX  (OFF_D + (size_t)84672512)    // 256 KB
#define WS_NEEDED ((size_t)203423744)

// ---------------- helpers ----------------
static __device__ __forceinline__ ushort_t f2bf(float f) {
    unsigned u = __float_as_uint(f);
    unsigned r = (u + 0x7fffu + ((u >> 16) & 1u)) >> 16;   // RNE
    return (ushort_t)r;
}
static __device__ __forceinline__ float bf2f(ushort_t h) {
    return __uint_as_float(((unsigned)h) << 16);
}
static __device__ __forceinline__ void pack3(float v, ushort_t* A, ushort_t* Bq,
                                             size_t base, int f) {
    ushort_t hi = f2bf(v);
    ushort_t lo = f2bf(v - bf2f(hi));
    A[base + f] = hi; A[base + H_ + f] = lo; A[base + 2 * H_ + f] = hi;
    if (Bq) { Bq[base + f] = hi; Bq[base + H_ + f] = hi; Bq[base + 2 * H_ + f] = lo; }
}

// ---------------- kernels ----------------

// h = x @ Wf + bf ; also pack h into Apack
__global__ void feat_pack(const float* __restrict__ x, const float* __restrict__ Wf,
                          const float* __restrict__ bfv, float* __restrict__ h,
                          ushort_t* __restrict__ Ap) {
    int pt = blockIdx.x;
    int f  = threadIdx.x;
    float x0 = x[pt * 3 + 0], x1 = x[pt * 3 + 1], x2 = x[pt * 3 + 2];
    float v = x0 * Wf[f] + x1 * Wf[H_ + f] + x2 * Wf[2 * H_ + f] + bfv[f];
    h[(size_t)pt * H_ + f] = v;
    pack3(v, Ap, nullptr, (size_t)pt * KP_, f);
}

// W (256 x Nd) -> Qpack (Nd x 768) rows [hi,hi,lo] of W^T
__global__ void pack_wT(const float* __restrict__ W, ushort_t* __restrict__ Qp, int Nd) {
    int n = blockIdx.x, k = threadIdx.x;
    float w = W[(size_t)k * Nd + n];
    ushort_t hi = f2bf(w), lo = f2bf(w - bf2f(hi));
    size_t base = (size_t)n * KP_;
    Qp[base + k] = hi; Qp[base + H_ + k] = hi; Qp[base + 2 * H_ + k] = lo;
}

// Qcat for fused u|v gemm: rows 0..255 = (We_a - We_b)^T, rows 256..511 = We_b^T
__global__ void pack_qcat(const float* __restrict__ We_l, const float* __restrict__ be_l,
                          ushort_t* __restrict__ Qp, float* __restrict__ bcat) {
    int n = blockIdx.x, k = threadIdx.x;
    float w;
    if (n < H_) w = We_l[(size_t)k * H_ + n] - We_l[(size_t)H_ * H_ + (size_t)k * H_ + n];
    else        w = We_l[(size_t)H_ * H_ + (size_t)k * H_ + (n - H_)];
    ushort_t hi = f2bf(w), lo = f2bf(w - bf2f(hi));
    size_t base = (size_t)n * KP_;
    Qp[base + k] = hi; Qp[base + H_ + k] = hi; Qp[base + 2 * H_ + k] = lo;
    if (k == 0) bcat[n] = (n < H_) ? be_l[n] : 0.f;
}

// ---- split-bf16 MFMA GEMM: out = P (M x K) . Q^T (N x K) ----
// mode 0: out[r][c] = acc + aux[c]
// mode 2: out[r][c] = resid[r][c] + alphap[aidx]*(acc+aux[c])
__global__ __launch_bounds__(256) void mfma_gemm(
    const ushort_t* __restrict__ P, const ushort_t* __restrict__ Q,
    const float* __restrict__ aux, float* __restrict__ out,
    int Kd, int ldOut, int mode, const float* __restrict__ resid,
    const float* __restrict__ alphap, int aidx) {
    __shared__ __align__(16) ushort_t As[128 * 32];
    __shared__ __align__(16) ushort_t Bs[128 * 32];
    int i0 = blockIdx.y * 128, j0 = blockIdx.x * 128;
    int tid = threadIdx.x;
    int lane = tid & 63, wave = tid >> 6;
    int wm = wave & 1, wn = wave >> 1;
    int m16 = lane & 15, kq = (lane >> 4) * 8;

    f32x4 acc[4][4];
    f32x4 zero = {0.f, 0.f, 0.f, 0.f};
#pragma unroll
    for (int i = 0; i < 4; ++i)
#pragma unroll
        for (int j = 0; j < 4; ++j) acc[i][j] = zero;

    int srow = tid >> 2;
    int skc  = (tid & 3) * 8;

    for (int k0 = 0; k0 < Kd; k0 += 32) {
#pragma unroll
        for (int s = 0; s < 2; ++s) {
            int row = srow + s * 64;
            const ushort_t* gpA = P + (size_t)(i0 + row) * Kd + k0 + skc;
            const ushort_t* gpB = Q + (size_t)(j0 + row) * Kd + k0 + skc;
            __builtin_amdgcn_global_load_lds(
                (const __attribute__((address_space(1))) void*)gpA,
                (__attribute__((address_space(3))) void*)(As + (size_t)(wave * 64 + s * 256) * 8),
                16, 0, 0);
            __builtin_amdgcn_global_load_lds(
                (const __attribute__((address_space(1))) void*)gpB,
                (__attribute__((address_space(3))) void*)(Bs + (size_t)(wave * 64 + s * 256) * 8),
                16, 0, 0);
        }
        __syncthreads();
        short8 af[4], bfr[4];
#pragma unroll
        for (int fi = 0; fi < 4; ++fi)
            af[fi] = *(const short8*)(As + (wm * 64 + fi * 16 + m16) * 32 + kq);
#pragma unroll
        for (int fj = 0; fj < 4; ++fj)
            bfr[fj] = *(const short8*)(Bs + (wn * 64 + fj * 16 + m16) * 32 + kq);
#pragma unroll
        for (int fi = 0; fi < 4; ++fi)
#pragma unroll
            for (int fj = 0; fj < 4; ++fj)
                acc[fi][fj] = __builtin_amdgcn_mfma_f32_16x16x32_bf16(
                    af[fi], bfr[fj], acc[fi][fj], 0, 0, 0);
        __syncthreads();
    }
    float alpha = (mode == 2) ? alphap[aidx] : 0.f;
    int rbase = i0 + wm * 64 + (lane >> 4) * 4;
    int cbase = j0 + wn * 64 + m16;
#pragma unroll
    for (int fi = 0; fi < 4; ++fi) {
#pragma unroll
        for (int fj = 0; fj < 4; ++fj) {
            int c = cbase + fj * 16;
            float a = aux[c];
#pragma unroll
            for (int r = 0; r < 4; ++r) {
                int gr = rbase + fi * 16 + r;
                size_t oidx = (size_t)gr * ldOut + c;
                float val;
                if (mode == 2) val = resid[oidx] + alpha * (acc[fi][fj][r] + a);
                else           val = acc[fi][fj][r] + a;
                out[oidx] = val;
            }
        }
    }
}

// per-point squared norm (fp32 activations)
__global__ void sqnorm(const float* __restrict__ X, float* __restrict__ sq) {
    int w = threadIdx.x >> 6, lane = threadIdx.x & 63;
    int pt = blockIdx.x * 4 + w;
    const float* xp = X + (size_t)pt * H_;
    float s = 0.f;
    for (int k = lane; k < H_; k += 64) { float v = xp[k]; s += v * v; }
#pragma unroll
    for (int off = 32; off; off >>= 1) s += __shfl_down(s, off);
    if (lane == 0) sq[pt] = s;
}

// ---- fused gram + top-16: never materializes D ----
// WG = one batch z, 32-row strip; streams 256-col MFMA tiles over all 2048 cols,
// keeps per-row sorted top-16 by (dist, col) lex in LDS (matches XLA tie-break).
__global__ __launch_bounds__(256) void gram_topk(const ushort_t* __restrict__ Ap,
                                                 const ushort_t* __restrict__ Bq,
                                                 const float* __restrict__ sqb,
                                                 int* __restrict__ idxb) {
    __shared__ __align__(16) ushort_t As[RWG_ * 32];   // 2 KB
    __shared__ __align__(16) ushort_t Bs[TW_ * 32];    // 16 KB
    __shared__ float topv[RWG_ * 16];
    __shared__ int   topc[RWG_ * 16];
    __shared__ float qv[RWG_ * CAP_];
    __shared__ int   qc[RWG_ * CAP_];
    __shared__ int   qn[RWG_];
    __shared__ int   ovf;

    int blk = blockIdx.x;
    int z = blk & 7;                 // batch -> XCD pin (L2 locality heuristic)
    int strip = blk >> 3;            // 0..63
    int r0 = strip * RWG_;
    const ushort_t* Pa = Ap + ((size_t)z * N_ + r0) * KP_;
    const ushort_t* Qb = Bq + (size_t)z * N_ * KP_;
    const float* sqz = sqb + (size_t)z * N_;

    int tid = threadIdx.x;
    int lane = tid & 63, wave = tid >> 6;
    int m16 = lane & 15, q4 = lane >> 4;
    int kq = q4 * 8;

    for (int i = tid; i < RWG_ * 16; i += 256) { topv[i] = FLT_MAX; topc[i] = 0x7fffffff; }
    if (tid < RWG_) qn[tid] = 0;
    if (tid == 0) ovf = 0;
    __syncthreads();

    for (int jt = 0; jt < N_ / TW_; ++jt) {
        int j0 = jt * TW_;
        f32x4 acc[2][4];
        f32x4 zero = {0.f, 0.f, 0.f, 0.f};
#pragma unroll
        for (int fi = 0; fi < 2; ++fi)
#pragma unroll
            for (int fj = 0; fj < 4; ++fj) acc[fi][fj] = zero;

        for (int k0 = 0; k0 < KP_; k0 += 32) {
            // stage A: 32 rows x 32k = 128 chunks (waves 0,1)
            if (tid < 128) {
                const ushort_t* gp = Pa + (size_t)(tid >> 2) * KP_ + k0 + (tid & 3) * 8;
                __builtin_amdgcn_global_load_lds(
                    (const __attribute__((address_space(1))) void*)gp,
                    (__attribute__((address_space(3))) void*)(As + (size_t)(wave * 64) * 8),
                    16, 0, 0);
            }
            // stage B: 256 cols x 32k = 1024 chunks (4 per thread)
#pragma unroll
            for (int s = 0; s < 4; ++s) {
                int c = s * 256 + tid;
                const ushort_t* gp = Qb + (size_t)(j0 + (c >> 2)) * KP_ + k0 + (c & 3) * 8;
                __builtin_amdgcn_global_load_lds(
                    (const __attribute__((address_space(1))) void*)gp,
                    (__attribute__((address_space(3))) void*)(Bs + (size_t)(s * 256 + wave * 64) * 8),
                    16, 0, 0);
            }
            __syncthreads();
            short8 af[2], bfr[4];
#pragma unroll
            for (int fi = 0; fi < 2; ++fi)
                af[fi] = *(const short8*)(As + (fi * 16 + m16) * 32 + kq);
#pragma unroll
            for (int fj = 0; fj < 4; ++fj)
                bfr[fj] = *(const short8*)(Bs + (wave * 64 + fj * 16 + m16) * 32 + kq);
#pragma unroll
            for (int fi = 0; fi < 2; ++fi)
#pragma unroll
                for (int fj = 0; fj < 4; ++fj)
                    acc[fi][fj] = __builtin_amdgcn_mfma_f32_16x16x32_bf16(
                        af[fi], bfr[fj], acc[fi][fj], 0, 0, 0);
            __syncthreads();
        }

        // epilogue: d = sq[col] - 2*acc ; streamed top-16 merge
        float scl[4];
#pragma unroll
        for (int fj = 0; fj < 4; ++fj) scl[fj] = sqz[j0 + wave * 64 + fj * 16 + m16];

        unsigned pend = 0xffffffffu;   // 2(fi) x 4(fj) x 4(reg) = 32 candidates/lane
        for (;;) {
            if (tid == 0) ovf = 0;
            __syncthreads();
#pragma unroll
            for (int fi = 0; fi < 2; ++fi) {
#pragma unroll
                for (int fj = 0; fj < 4; ++fj) {
#pragma unroll
                    for (int r = 0; r < 4; ++r) {
                        int bit = (fi << 4) | (fj << 2) | r;
                        if (!((pend >> bit) & 1u)) continue;
                        int rl = fi * 16 + q4 * 4 + r;          // local row
                        float v = scl[fj] - 2.f * acc[fi][fj][r];
                        int col = j0 + wave * 64 + fj * 16 + m16;
                        float tv = topv[rl * 16 + 15];
                        int   tc = topc[rl * 16 + 15];
                        if (v < tv || (v == tv && col < tc)) {
                            int slot = atomicAdd(&qn[rl], 1);
                            if (slot < CAP_) {
                                qv[rl * CAP_ + slot] = v;
                                qc[rl * CAP_ + slot] = col;
                                pend &= ~(1u << bit);
                            } else {
                                ovf = 1;   // retry next pass
                            }
                        } else {
                            pend &= ~(1u << bit);   // thr only tightens: drop forever
                        }
                    }
                }
            }
            __syncthreads();
            if (tid < RWG_) {   // drain row tid serially (32 rows in parallel)
                int cnt = qn[tid];
                if (cnt > CAP_) cnt = CAP_;
                float* tvp = topv + tid * 16;
                int*   tcp = topc + tid * 16;
                for (int i = 0; i < cnt; ++i) {
                    float v = qv[tid * CAP_ + i];
                    int   c = qc[tid * CAP_ + i];
                    if (v < tvp[15] || (v == tvp[15] && c < tcp[15])) {
                        int k = 15;
                        while (k > 0 && (tvp[k - 1] > v ||
                                         (tvp[k - 1] == v && tcp[k - 1] > c))) {
                            tvp[k] = tvp[k - 1]; tcp[k] = tcp[k - 1]; --k;
                        }
                        tvp[k] = v; tcp[k] = c;
                    }
                }
                qn[tid] = 0;
            }
            __syncthreads();
            if (!ovf) break;
        }
    }
    // write indices: 32 rows x 16 = 512 entries
    for (int i = tid; i < RWG_ * 16; i += 256)
        idxb[((size_t)z * N_ + r0 + (i >> 4)) * 16 + (i & 15)] = topc[i];
}

// t[b,i,h] = uv[row][h] + max_k uv[(b,idx_k)][256+h]
__global__ void gather_max(const float* __restrict__ uv, const int* __restrict__ idxb,
                           float* __restrict__ outp) {
    int row = blockIdx.x;
    int b = row >> 11;
    int h = threadIdx.x;
    const int* ip = idxb + row * 16;
    float m = -FLT_MAX;
#pragma unroll
    for (int k = 0; k < 16; ++k) {
        int j = ip[k];
        m = fmaxf(m, uv[((size_t)((b << 11) + j)) * 512 + 256 + h]);
    }
    outp[(size_t)row * H_ + h] = uv[(size_t)row * 512 + h] + m;
}

// ---- batchnorm over (B,N) per feature ----
__global__ void bn_zero(double* s) { s[threadIdx.x] = 0.0; }

__global__ void bn_stats(const float* __restrict__ X, double* __restrict__ sums) {
    int f = threadIdx.x;
    int r0 = blockIdx.x * 64;
    double s = 0.0, s2 = 0.0;
    for (int r = 0; r < 64; ++r) {
        float v = X[(size_t)(r0 + r) * H_ + f];
        s += v; s2 += (double)v * v;
    }
    atomicAdd(&sums[f], s);
    atomicAdd(&sums[H_ + f], s2);
}

__global__ void bn_final(const double* __restrict__ sums, const float* __restrict__ g,
                         const float* __restrict__ b, float* __restrict__ scsh) {
    int f = threadIdx.x;
    double m  = sums[f] / (double)BN_;
    double var = sums[H_ + f] / (double)BN_ - m * m;
    double inv = 1.0 / sqrt(var + 1e-5);
    float sc = g[f] * (float)inv;
    scsh[f] = sc;
    scsh[H_ + f] = b[f] - (float)m * sc;
}

// BN+ReLU, fused with split-bf16 packing. xbf32/Bq optional.
__global__ void bn_apply_pack(const float* __restrict__ X, const float* __restrict__ scsh,
                              float* __restrict__ xbf32, ushort_t* __restrict__ Ap,
                              ushort_t* __restrict__ Bq) {
    int row = blockIdx.x, f = threadIdx.x;
    float v = X[(size_t)row * H_ + f] * scsh[f] + scsh[H_ + f];
    v = fmaxf(v, 0.f);
    if (xbf32) xbf32[(size_t)row * H_ + f] = v;
    pack3(v, Ap, Bq, (size_t)row * KP_, f);
}

__global__ void maxpool1(const float* __restrict__ y, float* __restrict__ pmax) {
    int b = blockIdx.x, gc = blockIdx.y, nc = blockIdx.z;
    int g = gc * 256 + threadIdx.x;
    const float* yb = y + ((size_t)b * N_ + (size_t)nc * 128) * G_;
    float m = -FLT_MAX;
    for (int n = 0; n < 128; ++n) m = fmaxf(m, yb[(size_t)n * G_ + g]);
    pmax[((size_t)(b * 16 + nc)) * G_ + g] = m;
}

__global__ void maxpool2(const float* __restrict__ pmax, float* __restrict__ p) {
    int b = blockIdx.x;
    int g = blockIdx.y * 256 + threadIdx.x;
    float m = -FLT_MAX;
    for (int c = 0; c < 16; ++c) m = fmaxf(m, pmax[((size_t)(b * 16 + c)) * G_ + g]);
    p[(size_t)b * G_ + g] = m;
}

// parallel split-K head gemm: grid(M, Nd/64), 256 thr = 64 cols x 4 k-slices
__global__ __launch_bounds__(256) void head_gemm(const float* __restrict__ A,
                                                 const float* __restrict__ W,
                                                 const float* __restrict__ bias,
                                                 float* __restrict__ Cc,
                                                 int Kd, int Nd, int relu) {
    int m = blockIdx.x;
    int c0 = blockIdx.y * 64;
    int cl = threadIdx.x & 63;
    int ks = threadIdx.x >> 6;
    int kper = Kd >> 2;
    const float* Ap = A + (size_t)m * Kd + (size_t)ks * kper;
    const float* Wp = W + (size_t)ks * kper * Nd + c0 + cl;
    float acc = 0.f;
    for (int k = 0; k < kper; k += 8) {
#pragma unroll
        for (int u2 = 0; u2 < 8; ++u2)
            acc += Ap[k + u2] * Wp[(size_t)(k + u2) * Nd];
    }
    __shared__ float red[4][64];
    red[ks][cl] = acc;
    __syncthreads();
    if (ks == 0) {
        float s = red[0][cl] + red[1][cl] + red[2][cl] + red[3][cl] + bias[c0 + cl];
        if (relu) s = fmaxf(s, 0.f);
        Cc[(size_t)m * Nd + c0 + cl] = s;
    }
}

// ---------------- launch ----------------
extern "C" void kernel_launch(void* const* d_in, const int* in_sizes, int n_in,
                              void* d_out, int out_size, void* d_ws, size_t ws_size,
                              hipStream_t stream) {
    (void)in_sizes; (void)n_in; (void)out_size;
    if (ws_size < WS_NEEDED) return;

    const float* x    = (const float*)d_in[0];
    const float* Wf   = (const float*)d_in[2];
    const float* bfv  = (const float*)d_in[3];
    const float* Wnn  = (const float*)d_in[4];
    const float* bnn  = (const float*)d_in[5];
    const float* g1   = (const float*)d_in[6];
    const float* b1   = (const float*)d_in[7];
    const float* We   = (const float*)d_in[8];
    const float* be   = (const float*)d_in[9];
    const float* g2   = (const float*)d_in[10];
    const float* b2   = (const float*)d_in[11];
    const float* Wl   = (const float*)d_in[12];
    const float* bl   = (const float*)d_in[13];
    const float* alpha= (const float*)d_in[14];
    const float* gg   = (const float*)d_in[15];
    const float* bgb  = (const float*)d_in[16];
    const float* Wg   = (const float*)d_in[17];
    const float* bg2  = (const float*)d_in[18];
    const float* Wm1  = (const float*)d_in[19];
    const float* bm1  = (const float*)d_in[20];
    const float* Wm2  = (const float*)d_in[21];
    const float* bm2  = (const float*)d_in[22];
    const float* Wm3  = (const float*)d_in[23];
    const float* bm3  = (const float*)d_in[24];
    float* outp = (float*)d_out;

    char* ws = (char*)d_ws;
    float*    h    = (float*)(ws + OFF_H);
    ushort_t* Ap   = (ushort_t*)(ws + OFF_APACK);
    ushort_t* Bq   = (ushort_t*)(ws + OFF_BPACK);
    float*    sqb  = (float*)(ws + OFF_SQ);
    int*      idxb = (int*)  (ws + OFF_IDX);
    double*   stats= (double*)(ws + OFF_STATS);
    float*    scsh = (float*)(ws + OFF_SCSH);
    float*    bcat = (float*)(ws + OFF_BCAT);
    float*    p0   = (float*)(ws + OFF_P0);
    float*    p1   = (float*)(ws + OFF_P1);
    float*    p2   = (float*)(ws + OFF_P2);
    float*    t    = (float*)(ws + OFF_T);
    float*    xb   = (float*)(ws + OFF_XB);
    float*    uv   = (float*)(ws + OFF_UV);
    float*    y    = (float*)(ws + OFF_UV);
    ushort_t* Qw   = (ushort_t*)(ws + OFF_QW);
    float*    pmax = (float*)(ws + OFF_PMAX);

    auto bn_pre = [&](const float* src, const float* g, const float* b) {
        hipLaunchKernelGGL(bn_zero, dim3(1), dim3(512), 0, stream, stats);
        hipLaunchKernelGGL(bn_stats, dim3(256), dim3(256), 0, stream, src, stats);
        hipLaunchKernelGGL(bn_final, dim3(1), dim3(256), 0, stream, stats, g, b, scsh);
    };

    // h = x@Wf+bf (+pack), t = h@Wnn+bnn via MFMA
    hipLaunchKernelGGL(feat_pack, dim3(BN_), dim3(256), 0, stream, x, Wf, bfv, h, Ap);
    hipLaunchKernelGGL(pack_wT, dim3(H_), dim3(256), 0, stream, Wnn, Qw, H_);
    hipLaunchKernelGGL(mfma_gemm, dim3(2, 128), dim3(256), 0, stream,
                       Ap, Qw, bnn, t, KP_, H_, 0,
                       (const float*)nullptr, (const float*)nullptr, 0);

    for (int l = 0; l < L_; ++l) {
        const float* src1 = (l == 0) ? t : h;
        bn_pre(src1, g1 + l * H_, b1 + l * H_);
        hipLaunchKernelGGL(bn_apply_pack, dim3(BN_), dim3(256), 0, stream,
                           src1, scsh, xb, Ap, Bq);
        hipLaunchKernelGGL(sqnorm, dim3(BN_ / 4), dim3(256), 0, stream, xb, sqb);
        // fused gram + top-16 (D never materialized)
        hipLaunchKernelGGL(gram_topk, dim3(512), dim3(256), 0, stream,
                           Ap, Bq, sqb, idxb);
        // fused u|v gemm (N=512)
        hipLaunchKernelGGL(pack_qcat, dim3(512), dim3(256), 0, stream,
                           We + (size_t)l * 2 * H_ * H_, be + (size_t)l * H_, Qw, bcat);
        hipLaunchKernelGGL(mfma_gemm, dim3(4, 128), dim3(256), 0, stream,
                           Ap, Qw, bcat, uv, KP_, 512, 0,
                           (const float*)nullptr, (const float*)nullptr, 0);
        hipLaunchKernelGGL(gather_max, dim3(BN_), dim3(256), 0, stream, uv, idxb, t);
        // BN2 + Wl with fused residual: h = h + alpha[l]*(xb@Wl + bl)
        bn_pre(t, g2 + l * H_, b2 + l * H_);
        hipLaunchKernelGGL(bn_apply_pack, dim3(BN_), dim3(256), 0, stream,
                           t, scsh, (float*)nullptr, Ap, (ushort_t*)nullptr);
        hipLaunchKernelGGL(pack_wT, dim3(H_), dim3(256), 0, stream,
                           Wl + (size_t)l * H_ * H_, Qw, H_);
        hipLaunchKernelGGL(mfma_gemm, dim3(2, 128), dim3(256), 0, stream,
                           Ap, Qw, bl + (size_t)l * H_, h, KP_, H_, 2,
                           h, alpha, l);
    }

    // head
    bn_pre(h, gg, bgb);
    hipLaunchKernelGGL(bn_apply_pack, dim3(BN_), dim3(256), 0, stream,
                       h, scsh, (float*)nullptr, Ap, (ushort_t*)nullptr);
    hipLaunchKernelGGL(pack_wT, dim3(G_), dim3(256), 0, stream, Wg, Qw, G_);
    hipLaunchKernelGGL(mfma_gemm, dim3(4, 128), dim3(256), 0, stream,
                       Ap, Qw, bg2, y, KP_, G_, 0,
                       (const float*)nullptr, (const float*)nullptr, 0);
    hipLaunchKernelGGL(maxpool1, dim3(8, 2, 16), dim3(256), 0, stream, y, pmax);
    hipLaunchKernelGGL(maxpool2, dim3(8, 2), dim3(256), 0, stream, pmax, p0);
    hipLaunchKernelGGL(head_gemm, dim3(8, 4), dim3(256), 0, stream, p0, Wm1, bm1, p1, G_, M0_, 1);
    hipLaunchKernelGGL(head_gemm, dim3(8, 2), dim3(256), 0, stream, p1, Wm2, bm2, p2, M0_, M1_, 1);
    hipLaunchKernelGGL(head_gemm, dim3(8, 2), dim3(256), 0, stream, p2, Wm3, bm3, outp, M1_, C_, 0);
}

// Round 6
// 1424.284 us; speedup vs baseline: 1.7617x; 1.7617x over previous
//
#include <hip/hip_runtime.h>
#include <cfloat>

#define B_  8
#define N_  2048
#define H_  256
#define L_  4
#define K_  16
#define G_  512
#define M0_ 256
#define M1_ 128
#define C_  128
#define BN_ 16384   // B_*N_
#define KP_ 768     // packed split-bf16 K (3*H_)

typedef unsigned short ushort_t;
typedef __attribute__((ext_vector_type(8))) short short8;
typedef __attribute__((ext_vector_type(4))) float f32x4;

// ---------------- workspace layout (bytes) ----------------
#define OFF_H     ((size_t)0)            // 16 MB  h (fp32, persistent)
#define OFF_APACK ((size_t)16777216)     // 25.2 MB  P-pack [hi,lo,hi] (Q read via seg remap)
#define OFF_SQ    ((size_t)67108864)     // 64 KB
#define OFF_IDX   ((size_t)67174400)     // 1 MB
#define OFF_STATS ((size_t)68222976)     // 4 KB (512 doubles)
#define OFF_SCSH  ((size_t)68227072)     // 2 KB
#define OFF_BCAT  ((size_t)68229120)     // 2 KB
#define OFF_P0    ((size_t)68231168)     // 16 KB
#define OFF_P1    ((size_t)68247552)
#define OFF_P2    ((size_t)68255744)
#define OFF_D     ((size_t)69206016)     // 134.2 MB dmat; overlays below (stream-ordered safe)
#define OFF_T     (OFF_D + (size_t)0)           // 16 MB (alive gather_max -> bn2; dmat dead)
#define OFF_UV    (OFF_D + (size_t)50331648)    // 33.5 MB (alive uv gemm -> gather); also y
#define OFF_QW    (OFF_D + (size_t)83886080)    // 0.79 MB weight packs
#define OFF_PMAX  (OFF_D + (size_t)84672512)    // 256 KB
#define WS_NEEDED ((size_t)203423744)

// ---------------- helpers ----------------
static __device__ __forceinline__ ushort_t f2bf(float f) {
    unsigned u = __float_as_uint(f);
    unsigned r = (u + 0x7fffu + ((u >> 16) & 1u)) >> 16;   // RNE
    return (ushort_t)r;
}
static __device__ __forceinline__ float bf2f(ushort_t h) {
    return __uint_as_float(((unsigned)h) << 16);
}
// P-pack layout per row: [hi(0:256), lo(256:512), hi(512:768)]
static __device__ __forceinline__ void pack3(float v, ushort_t* A, size_t base, int f) {
    ushort_t hi = f2bf(v);
    ushort_t lo = f2bf(v - bf2f(hi));
    A[base + f] = hi; A[base + H_ + f] = lo; A[base + 2 * H_ + f] = hi;
}

// ---------------- kernels ----------------

// h = x @ Wf + bf ; also pack h into Apack
__global__ void feat_pack(const float* __restrict__ x, const float* __restrict__ Wf,
                          const float* __restrict__ bfv, float* __restrict__ h,
                          ushort_t* __restrict__ Ap) {
    int pt = blockIdx.x;
    int f  = threadIdx.x;
    float x0 = x[pt * 3 + 0], x1 = x[pt * 3 + 1], x2 = x[pt * 3 + 2];
    float v = x0 * Wf[f] + x1 * Wf[H_ + f] + x2 * Wf[2 * H_ + f] + bfv[f];
    h[(size_t)pt * H_ + f] = v;
    pack3(v, Ap, (size_t)pt * KP_, f);
}

// W (256 x Nd) -> Qpack (Nd x 768) rows [hi,hi,lo] of W^T
__global__ void pack_wT(const float* __restrict__ W, ushort_t* __restrict__ Qp, int Nd) {
    int n = blockIdx.x, k = threadIdx.x;
    float w = W[(size_t)k * Nd + n];
    ushort_t hi = f2bf(w), lo = f2bf(w - bf2f(hi));
    size_t base = (size_t)n * KP_;
    Qp[base + k] = hi; Qp[base + H_ + k] = hi; Qp[base + 2 * H_ + k] = lo;
}

// Qcat for fused u|v gemm: rows 0..255 = (We_a - We_b)^T, rows 256..511 = We_b^T
__global__ void pack_qcat(const float* __restrict__ We_l, const float* __restrict__ be_l,
                          ushort_t* __restrict__ Qp, float* __restrict__ bcat) {
    int n = blockIdx.x, k = threadIdx.x;
    float w;
    if (n < H_) w = We_l[(size_t)k * H_ + n] - We_l[(size_t)H_ * H_ + (size_t)k * H_ + n];
    else        w = We_l[(size_t)H_ * H_ + (size_t)k * H_ + (n - H_)];
    ushort_t hi = f2bf(w), lo = f2bf(w - bf2f(hi));
    size_t base = (size_t)n * KP_;
    Qp[base + k] = hi; Qp[base + H_ + k] = hi; Qp[base + 2 * H_ + k] = lo;
    if (k == 0) bcat[n] = (n < H_) ? be_l[n] : 0.f;
}

// ---- split-bf16 MFMA GEMM: out = P (M x K) . Q^T (N x K) ----
// mode 0: out[r][c] = acc + aux[c]
// mode 2: out[r][c] = resid[r][c] + alphap[aidx]*(acc+aux[c])
__global__ __launch_bounds__(256) void mfma_gemm(
    const ushort_t* __restrict__ P, const ushort_t* __restrict__ Q,
    const float* __restrict__ aux, float* __restrict__ out,
    int Kd, int ldOut, int mode, const float* __restrict__ resid,
    const float* __restrict__ alphap, int aidx) {
    __shared__ __align__(16) ushort_t As[128 * 32];
    __shared__ __align__(16) ushort_t Bs[128 * 32];
    int i0 = blockIdx.y * 128, j0 = blockIdx.x * 128;
    int tid = threadIdx.x;
    int lane = tid & 63, wave = tid >> 6;
    int wm = wave & 1, wn = wave >> 1;
    int m16 = lane & 15, kq = (lane >> 4) * 8;

    f32x4 acc[4][4];
    f32x4 zero = {0.f, 0.f, 0.f, 0.f};
#pragma unroll
    for (int i = 0; i < 4; ++i)
#pragma unroll
        for (int j = 0; j < 4; ++j) acc[i][j] = zero;

    int srow = tid >> 2;
    int skc  = (tid & 3) * 8;

    for (int k0 = 0; k0 < Kd; k0 += 32) {
#pragma unroll
        for (int s = 0; s < 2; ++s) {
            int row = srow + s * 64;
            const ushort_t* gpA = P + (size_t)(i0 + row) * Kd + k0 + skc;
            const ushort_t* gpB = Q + (size_t)(j0 + row) * Kd + k0 + skc;
            __builtin_amdgcn_global_load_lds(
                (const __attribute__((address_space(1))) void*)gpA,
                (__attribute__((address_space(3))) void*)(As + (size_t)(wave * 64 + s * 256) * 8),
                16, 0, 0);
            __builtin_amdgcn_global_load_lds(
                (const __attribute__((address_space(1))) void*)gpB,
                (__attribute__((address_space(3))) void*)(Bs + (size_t)(wave * 64 + s * 256) * 8),
                16, 0, 0);
        }
        __syncthreads();
        short8 af[4], bfr[4];
#pragma unroll
        for (int fi = 0; fi < 4; ++fi)
            af[fi] = *(const short8*)(As + (wm * 64 + fi * 16 + m16) * 32 + kq);
#pragma unroll
        for (int fj = 0; fj < 4; ++fj)
            bfr[fj] = *(const short8*)(Bs + (wn * 64 + fj * 16 + m16) * 32 + kq);
#pragma unroll
        for (int fi = 0; fi < 4; ++fi)
#pragma unroll
            for (int fj = 0; fj < 4; ++fj)
                acc[fi][fj] = __builtin_amdgcn_mfma_f32_16x16x32_bf16(
                    af[fi], bfr[fj], acc[fi][fj], 0, 0, 0);
        __syncthreads();
    }
    float alpha = (mode == 2) ? alphap[aidx] : 0.f;
    int rbase = i0 + wm * 64 + (lane >> 4) * 4;
    int cbase = j0 + wn * 64 + m16;
#pragma unroll
    for (int fi = 0; fi < 4; ++fi) {
#pragma unroll
        for (int fj = 0; fj < 4; ++fj) {
            int c = cbase + fj * 16;
            float a = aux[c];
#pragma unroll
            for (int r = 0; r < 4; ++r) {
                int gr = rbase + fi * 16 + r;
                size_t oidx = (size_t)gr * ldOut + c;
                float val;
                if (mode == 2) val = resid[oidx] + alpha * (acc[fi][fj][r] + a);
                else           val = acc[fi][fj][r] + a;
                out[oidx] = val;
            }
        }
    }
}

// ---- symmetric gram: D[i][j] = sq[j] - 2 <x_i, x_j>, upper-tri tile pairs only ----
// grid.x = 136 (pair id, bi<=bj over 16 tile-rows), grid.y = 8 (batch).
// B-side reads P-pack with segment remap (0,2,1) to realize Q = [hi,hi,lo].
__global__ __launch_bounds__(256) void gram_sym(const ushort_t* __restrict__ Ap,
                                                const float* __restrict__ sqb,
                                                float* __restrict__ D) {
    __shared__ __align__(16) ushort_t As[128 * 32];
    __shared__ __align__(16) ushort_t Bs[128 * 32];
    int z = blockIdx.y;
    int p = blockIdx.x;
    int bi = 0, rem = p;
    while (rem >= 16 - bi) { rem -= 16 - bi; ++bi; }
    int bj = bi + rem;
    const ushort_t* Pz = Ap + (size_t)z * N_ * KP_;
    const float* sqz = sqb + (size_t)z * N_;
    float* Dz = D + (size_t)z * N_ * N_;
    int i0 = bi * 128, j0 = bj * 128;

    int tid = threadIdx.x;
    int lane = tid & 63, wave = tid >> 6;
    int wm = wave & 1, wn = wave >> 1;
    int m16 = lane & 15, kq = (lane >> 4) * 8;

    f32x4 acc[4][4];
    f32x4 zero = {0.f, 0.f, 0.f, 0.f};
#pragma unroll
    for (int i = 0; i < 4; ++i)
#pragma unroll
        for (int j = 0; j < 4; ++j) acc[i][j] = zero;

    int srow = tid >> 2;
    int skc  = (tid & 3) * 8;

    for (int k0 = 0; k0 < KP_; k0 += 32) {
        // Q segment remap: seg0->seg0(hi), seg1->seg2(hi), seg2->seg1(lo)
        int kb = (k0 < 256) ? k0 : ((k0 < 512) ? k0 + 256 : k0 - 256);
#pragma unroll
        for (int s = 0; s < 2; ++s) {
            int row = srow + s * 64;
            const ushort_t* gpA = Pz + (size_t)(i0 + row) * KP_ + k0 + skc;
            const ushort_t* gpB = Pz + (size_t)(j0 + row) * KP_ + kb + skc;
            __builtin_amdgcn_global_load_lds(
                (const __attribute__((address_space(1))) void*)gpA,
                (__attribute__((address_space(3))) void*)(As + (size_t)(wave * 64 + s * 256) * 8),
                16, 0, 0);
            __builtin_amdgcn_global_load_lds(
                (const __attribute__((address_space(1))) void*)gpB,
                (__attribute__((address_space(3))) void*)(Bs + (size_t)(wave * 64 + s * 256) * 8),
                16, 0, 0);
        }
        __syncthreads();
        short8 af[4], bfr[4];
#pragma unroll
        for (int fi = 0; fi < 4; ++fi)
            af[fi] = *(const short8*)(As + (wm * 64 + fi * 16 + m16) * 32 + kq);
#pragma unroll
        for (int fj = 0; fj < 4; ++fj)
            bfr[fj] = *(const short8*)(Bs + (wn * 64 + fj * 16 + m16) * 32 + kq);
#pragma unroll
        for (int fi = 0; fi < 4; ++fi)
#pragma unroll
            for (int fj = 0; fj < 4; ++fj)
                acc[fi][fj] = __builtin_amdgcn_mfma_f32_16x16x32_bf16(
                    af[fi], bfr[fj], acc[fi][fj], 0, 0, 0);
        __syncthreads();
    }
    int rbase = i0 + wm * 64 + (lane >> 4) * 4;
    int cbase = j0 + wn * 64 + m16;
#pragma unroll
    for (int fi = 0; fi < 4; ++fi) {
        int gr0 = rbase + fi * 16;
        float4 s4 = *(const float4*)(sqz + gr0);   // sq of this lane's 4 rows
        float sr[4] = {s4.x, s4.y, s4.z, s4.w};
#pragma unroll
        for (int fj = 0; fj < 4; ++fj) {
            int c = cbase + fj * 16;
            float sc = sqz[c];
#pragma unroll
            for (int r = 0; r < 4; ++r)
                __builtin_nontemporal_store(sc - 2.f * acc[fi][fj][r],
                                            Dz + (size_t)(gr0 + r) * N_ + c);
            if (bi != bj) {   // transposed tile: D[c][gr0..gr0+3], contiguous 16B
                f32x4 o;
                o[0] = sr[0] - 2.f * acc[fi][fj][0];
                o[1] = sr[1] - 2.f * acc[fi][fj][1];
                o[2] = sr[2] - 2.f * acc[fi][fj][2];
                o[3] = sr[3] - 2.f * acc[fi][fj][3];
                __builtin_nontemporal_store(o, (f32x4*)(Dz + (size_t)c * N_ + gr0));
            }
        }
    }
}

// wave-per-row top-16 smallest (ties -> smaller index)
__global__ __launch_bounds__(256) void topk16(const float* __restrict__ D,
                                              int* __restrict__ idxb) {
    int w = threadIdx.x >> 6, lane = threadIdx.x & 63;
    int row = blockIdx.x * 4 + w;
    const float* dp = D + (size_t)row * N_;
    float lv[32];
#pragma unroll
    for (int t = 0; t < 32; ++t) lv[t] = __builtin_nontemporal_load(dp + lane + (t << 6));
    unsigned mask = 0;
    for (int it = 0; it < 16; ++it) {
        float bv = FLT_MAX;
        int bt = 0;
#pragma unroll
        for (int t = 0; t < 32; ++t) {
            bool ok = (((mask >> t) & 1u) == 0u) && (lv[t] < bv);
            bv = ok ? lv[t] : bv;
            bt = ok ? t : bt;
        }
        unsigned sb = __float_as_uint(bv);
        sb = (sb & 0x80000000u) ? ~sb : (sb | 0x80000000u);
        unsigned j = (unsigned)lane + ((unsigned)bt << 6);
        unsigned long long key = ((unsigned long long)sb << 32) | j;
#pragma unroll
        for (int off = 32; off; off >>= 1) {
            unsigned long long o = __shfl_xor(key, off);
            key = (o < key) ? o : key;
        }
        unsigned jw = (unsigned)(key & 0xffffffffu);
        if ((unsigned)lane == (jw & 63u)) mask |= 1u << (jw >> 6);
        if (lane == 0) idxb[row * 16 + it] = (int)jw;
    }
}

// t[b,i,h] = uv[row][h] + max_k uv[(b,idx_k)][256+h]
__global__ void gather_max(const float* __restrict__ uv, const int* __restrict__ idxb,
                           float* __restrict__ outp) {
    int row = blockIdx.x;
    int b = row >> 11;
    int h = threadIdx.x;
    const int* ip = idxb + row * 16;
    float m = -FLT_MAX;
#pragma unroll
    for (int k = 0; k < 16; ++k) {
        int j = ip[k];
        m = fmaxf(m, uv[((size_t)((b << 11) + j)) * 512 + 256 + h]);
    }
    outp[(size_t)row * H_ + h] = uv[(size_t)row * 512 + h] + m;
}

// ---- batchnorm over (B,N) per feature ----
__global__ void bn_zero(double* s) { s[threadIdx.x] = 0.0; }

__global__ void bn_stats(const float* __restrict__ X, double* __restrict__ sums) {
    int f = threadIdx.x;
    int r0 = blockIdx.x * 64;
    double s = 0.0, s2 = 0.0;
    for (int r = 0; r < 64; ++r) {
        float v = X[(size_t)(r0 + r) * H_ + f];
        s += v; s2 += (double)v * v;
    }
    atomicAdd(&sums[f], s);
    atomicAdd(&sums[H_ + f], s2);
}

__global__ void bn_final(const double* __restrict__ sums, const float* __restrict__ g,
                         const float* __restrict__ b, float* __restrict__ scsh) {
    int f = threadIdx.x;
    double m  = sums[f] / (double)BN_;
    double var = sums[H_ + f] / (double)BN_ - m * m;
    double inv = 1.0 / sqrt(var + 1e-5);
    float sc = g[f] * (float)inv;
    scsh[f] = sc;
    scsh[H_ + f] = b[f] - (float)m * sc;
}

// BN+ReLU fused with split-bf16 packing and (optional) row sqnorm reduce.
__global__ void bn_apply_pack(const float* __restrict__ X, const float* __restrict__ scsh,
                              ushort_t* __restrict__ Ap, float* __restrict__ sq) {
    int row = blockIdx.x, f = threadIdx.x;
    float v = X[(size_t)row * H_ + f] * scsh[f] + scsh[H_ + f];
    v = fmaxf(v, 0.f);
    pack3(v, Ap, (size_t)row * KP_, f);
    if (sq) {
        float s = v * v;
#pragma unroll
        for (int off = 32; off; off >>= 1) s += __shfl_down(s, off);
        __shared__ float red[4];
        if ((f & 63) == 0) red[f >> 6] = s;
        __syncthreads();
        if (f == 0) sq[row] = red[0] + red[1] + red[2] + red[3];
    }
}

__global__ void maxpool1(const float* __restrict__ y, float* __restrict__ pmax) {
    int b = blockIdx.x, gc = blockIdx.y, nc = blockIdx.z;
    int g = gc * 256 + threadIdx.x;
    const float* yb = y + ((size_t)b * N_ + (size_t)nc * 128) * G_;
    float m = -FLT_MAX;
    for (int n = 0; n < 128; ++n) m = fmaxf(m, yb[(size_t)n * G_ + g]);
    pmax[((size_t)(b * 16 + nc)) * G_ + g] = m;
}

__global__ void maxpool2(const float* __restrict__ pmax, float* __restrict__ p) {
    int b = blockIdx.x;
    int g = blockIdx.y * 256 + threadIdx.x;
    float m = -FLT_MAX;
    for (int c = 0; c < 16; ++c) m = fmaxf(m, pmax[((size_t)(b * 16 + c)) * G_ + g]);
    p[(size_t)b * G_ + g] = m;
}

// parallel split-K head gemm: grid(M, Nd/64), 256 thr = 64 cols x 4 k-slices
__global__ __launch_bounds__(256) void head_gemm(const float* __restrict__ A,
                                                 const float* __restrict__ W,
                                                 const float* __restrict__ bias,
                                                 float* __restrict__ Cc,
                                                 int Kd, int Nd, int relu) {
    int m = blockIdx.x;
    int c0 = blockIdx.y * 64;
    int cl = threadIdx.x & 63;
    int ks = threadIdx.x >> 6;
    int kper = Kd >> 2;
    const float* Ap = A + (size_t)m * Kd + (size_t)ks * kper;
    const float* Wp = W + (size_t)ks * kper * Nd + c0 + cl;
    float acc = 0.f;
    for (int k = 0; k < kper; k += 8) {
#pragma unroll
        for (int u2 = 0; u2 < 8; ++u2)
            acc += Ap[k + u2] * Wp[(size_t)(k + u2) * Nd];
    }
    __shared__ float red[4][64];
    red[ks][cl] = acc;
    __syncthreads();
    if (ks == 0) {
        float s = red[0][cl] + red[1][cl] + red[2][cl] + red[3][cl] + bias[c0 + cl];
        if (relu) s = fmaxf(s, 0.f);
        Cc[(size_t)m * Nd + c0 + cl] = s;
    }
}

// ---------------- launch ----------------
extern "C" void kernel_launch(void* const* d_in, const int* in_sizes, int n_in,
                              void* d_out, int out_size, void* d_ws, size_t ws_size,
                              hipStream_t stream) {
    (void)in_sizes; (void)n_in; (void)out_size;
    if (ws_size < WS_NEEDED) return;

    const float* x    = (const float*)d_in[0];
    const float* Wf   = (const float*)d_in[2];
    const float* bfv  = (const float*)d_in[3];
    const float* Wnn  = (const float*)d_in[4];
    const float* bnn  = (const float*)d_in[5];
    const float* g1   = (const float*)d_in[6];
    const float* b1   = (const float*)d_in[7];
    const float* We   = (const float*)d_in[8];
    const float* be   = (const float*)d_in[9];
    const float* g2   = (const float*)d_in[10];
    const float* b2   = (const float*)d_in[11];
    const float* Wl   = (const float*)d_in[12];
    const float* bl   = (const float*)d_in[13];
    const float* alpha= (const float*)d_in[14];
    const float* gg   = (const float*)d_in[15];
    const float* bgb  = (const float*)d_in[16];
    const float* Wg   = (const float*)d_in[17];
    const float* bg2  = (const float*)d_in[18];
    const float* Wm1  = (const float*)d_in[19];
    const float* bm1  = (const float*)d_in[20];
    const float* Wm2  = (const float*)d_in[21];
    const float* bm2  = (const float*)d_in[22];
    const float* Wm3  = (const float*)d_in[23];
    const float* bm3  = (const float*)d_in[24];
    float* outp = (float*)d_out;

    char* ws = (char*)d_ws;
    float*    h    = (float*)(ws + OFF_H);
    ushort_t* Ap   = (ushort_t*)(ws + OFF_APACK);
    float*    sqb  = (float*)(ws + OFF_SQ);
    int*      idxb = (int*)  (ws + OFF_IDX);
    double*   stats= (double*)(ws + OFF_STATS);
    float*    scsh = (float*)(ws + OFF_SCSH);
    float*    bcat = (float*)(ws + OFF_BCAT);
    float*    p0   = (float*)(ws + OFF_P0);
    float*    p1   = (float*)(ws + OFF_P1);
    float*    p2   = (float*)(ws + OFF_P2);
    float*    dmat = (float*)(ws + OFF_D);
    float*    t    = (float*)(ws + OFF_T);
    float*    uv   = (float*)(ws + OFF_UV);
    float*    y    = (float*)(ws + OFF_UV);
    ushort_t* Qw   = (ushort_t*)(ws + OFF_QW);
    float*    pmax = (float*)(ws + OFF_PMAX);

    auto bn_pre = [&](const float* src, const float* g, const float* b) {
        hipLaunchKernelGGL(bn_zero, dim3(1), dim3(512), 0, stream, stats);
        hipLaunchKernelGGL(bn_stats, dim3(256), dim3(256), 0, stream, src, stats);
        hipLaunchKernelGGL(bn_final, dim3(1), dim3(256), 0, stream, stats, g, b, scsh);
    };

    // h = x@Wf+bf (+pack), t = h@Wnn+bnn via MFMA
    hipLaunchKernelGGL(feat_pack, dim3(BN_), dim3(256), 0, stream, x, Wf, bfv, h, Ap);
    hipLaunchKernelGGL(pack_wT, dim3(H_), dim3(256), 0, stream, Wnn, Qw, H_);
    hipLaunchKernelGGL(mfma_gemm, dim3(2, 128), dim3(256), 0, stream,
                       Ap, Qw, bnn, t, KP_, H_, 0,
                       (const float*)nullptr, (const float*)nullptr, 0);

    for (int l = 0; l < L_; ++l) {
        const float* src1 = (l == 0) ? t : h;
        bn_pre(src1, g1 + l * H_, b1 + l * H_);
        hipLaunchKernelGGL(bn_apply_pack, dim3(BN_), dim3(256), 0, stream,
                           src1, scsh, Ap, sqb);
        // symmetric gram -> D (both triangles written, upper computed)
        hipLaunchKernelGGL(gram_sym, dim3(136, 8), dim3(256), 0, stream,
                           Ap, sqb, dmat);
        hipLaunchKernelGGL(topk16, dim3(BN_ / 4), dim3(256), 0, stream, dmat, idxb);
        // fused u|v gemm (N=512)
        hipLaunchKernelGGL(pack_qcat, dim3(512), dim3(256), 0, stream,
                           We + (size_t)l * 2 * H_ * H_, be + (size_t)l * H_, Qw, bcat);
        hipLaunchKernelGGL(mfma_gemm, dim3(4, 128), dim3(256), 0, stream,
                           Ap, Qw, bcat, uv, KP_, 512, 0,
                           (const float*)nullptr, (const float*)nullptr, 0);
        hipLaunchKernelGGL(gather_max, dim3(BN_), dim3(256), 0, stream, uv, idxb, t);
        // BN2 + Wl with fused residual: h = h + alpha[l]*(xb@Wl + bl)
        bn_pre(t, g2 + l * H_, b2 + l * H_);
        hipLaunchKernelGGL(bn_apply_pack, dim3(BN_), dim3(256), 0, stream,
                           t, scsh, Ap, (float*)nullptr);
        hipLaunchKernelGGL(pack_wT, dim3(H_), dim3(256), 0, stream,
                           Wl + (size_t)l * H_ * H_, Qw, H_);
        hipLaunchKernelGGL(mfma_gemm, dim3(2, 128), dim3(256), 0, stream,
                           Ap, Qw, bl + (size_t)l * H_, h, KP_, H_, 2,
                           h, alpha, l);
    }

    // head
    bn_pre(h, gg, bgb);
    hipLaunchKernelGGL(bn_apply_pack, dim3(BN_), dim3(256), 0, stream,
                       h, scsh, Ap, (float*)nullptr);
    hipLaunchKernelGGL(pack_wT, dim3(G_), dim3(256), 0, stream, Wg, Qw, G_);
    hipLaunchKernelGGL(mfma_gemm, dim3(4, 128), dim3(256), 0, stream,
                       Ap, Qw, bg2, y, KP_, G_, 0,
                       (const float*)nullptr, (const float*)nullptr, 0);
    hipLaunchKernelGGL(maxpool1, dim3(8, 2, 16), dim3(256), 0, stream, y, pmax);
    hipLaunchKernelGGL(maxpool2, dim3(8, 2), dim3(256), 0, stream, pmax, p0);
    hipLaunchKernelGGL(head_gemm, dim3(8, 4), dim3(256), 0, stream, p0, Wm1, bm1, p1, G_, M0_, 1);
    hipLaunchKernelGGL(head_gemm, dim3(8, 2), dim3(256), 0, stream, p1, Wm2, bm2, p2, M0_, M1_, 1);
    hipLaunchKernelGGL(head_gemm, dim3(8, 2), dim3(256), 0, stream, p2, Wm3, bm3, outp, M1_, C_, 0);
}